// Round 9
// baseline (244.260 us; speedup 1.0000x reference)
//
#include <hip/hip_runtime.h>

#define N_NODES 50000
#define N_REL 16
#define N_BASIS 8
#define D_IN 64
#define D_HID 64
#define N_CLASS 16
#define N_EDGES 800000
#define N_SBLK 196      // ceil(50000/256)
#define G1_BLOCKS 782   // ceil(50000/64)
#define CNT_BLOCKS 3125 // ceil(800000/256)

typedef short s8v __attribute__((ext_vector_type(8)));    // 8 bf16 (4 VGPRs) MFMA A/B frag
typedef float f4v __attribute__((ext_vector_type(4)));    // 4 fp32 MFMA C/D frag

__device__ inline unsigned short f2bf(float f) {
    union { float f; unsigned u; } v; v.f = f;
    unsigned r = (v.u + 0x7FFFu + ((v.u >> 16) & 1u)) >> 16;   // RNE
    return (unsigned short)r;
}
__device__ inline float bf2f(unsigned short b) {
    union { unsigned u; float f; } v; v.u = ((unsigned)b) << 16;
    return v.f;
}

// ---------------- weights: w1T[r][o][k], w2T[r][o][k] in bf16; slot r=16 = self ----------------
__global__ __launch_bounds__(256) void k_wrel(const float* __restrict__ b1, const float* __restrict__ c1,
                                              const float* __restrict__ s1f,
                                              const float* __restrict__ b2, const float* __restrict__ c2,
                                              const float* __restrict__ s2f,
                                              unsigned short* __restrict__ w1T,
                                              unsigned short* __restrict__ w2T) {
    int idx = blockIdx.x * 256 + threadIdx.x;
    if (idx < 17 * 4096) {
        int r = idx >> 12;            // 0..16
        int o = (idx >> 6) & 63;
        int k = idx & 63;
        float acc = 0.f;
        if (r < 16) {
            #pragma unroll
            for (int b = 0; b < N_BASIS; b++) acc += c1[r * N_BASIS + b] * b1[b * 4096 + k * 64 + o];
        } else {
            acc = s1f[k * 64 + o];
        }
        w1T[idx] = f2bf(acc);
    } else {
        int idx2 = idx - 17 * 4096;
        if (idx2 < 17 * 1024) {
            int r = idx2 >> 10;       // 0..16
            int o = (idx2 >> 6) & 15;
            int k = idx2 & 63;
            float acc = 0.f;
            if (r < 16) {
                #pragma unroll
                for (int b = 0; b < N_BASIS; b++) acc += c2[r * N_BASIS + b] * b2[b * 1024 + k * 16 + o];
            } else {
                acc = s2f[k * 16 + o];
            }
            w2T[idx2] = f2bf(acc);
        }
    }
}

// ---------------- FUSED: layer-1 MFMA transform (blocks 0..781)  ||  counts histogram (rest) ----
// gemm1: A = W^T rows o (LDS dbuf, XOR-swizzled), B = x node cols (regs).
// counts: node-major counts[dst*16+t], one 64B line per node.
__global__ __launch_bounds__(256) void k_fused1(const float* __restrict__ x,
                                                const unsigned short* __restrict__ w1T,
                                                unsigned short* __restrict__ t1,
                                                unsigned short* __restrict__ h,
                                                const int* __restrict__ ei,
                                                const int* __restrict__ et,
                                                int* __restrict__ counts) {
    if (blockIdx.x >= G1_BLOCKS) {
        int e = (blockIdx.x - G1_BLOCKS) * 256 + threadIdx.x;
        if (e < N_EDGES) {
            int dst = ei[N_EDGES + e];
            int t = et[e];
            atomicAdd(&counts[dst * 16 + t], 1);
        }
        return;
    }
    __shared__ __align__(16) unsigned short wbuf[2][64 * 64];   // 2 x 8 KB weight slices
    __shared__ __align__(16) unsigned short ou[4][16 * 64];     // per-wave epilogue tiles
    int tid = threadIdx.x;
    int wv = tid >> 6, lane = tid & 63;
    int m = lane & 15, q = lane >> 4;
    int nb = blockIdx.x * 64 + wv * 16;
    bool active = (nb < N_NODES);        // wave-uniform; inactive waves still hit barriers
    int n = active ? (nb + m) : 0;

    // B-fragments: x[n][k] fp32 -> bf16 in regs (held across all 17 weights)
    const float* xr = x + (size_t)n * 64 + q * 8;
    float4 x0a = *(const float4*)(xr);
    float4 x0b = *(const float4*)(xr + 4);
    float4 x1a = *(const float4*)(xr + 32);
    float4 x1b = *(const float4*)(xr + 36);
    s8v b0, b1;
    b0[0] = f2bf(x0a.x); b0[1] = f2bf(x0a.y); b0[2] = f2bf(x0a.z); b0[3] = f2bf(x0a.w);
    b0[4] = f2bf(x0b.x); b0[5] = f2bf(x0b.y); b0[6] = f2bf(x0b.z); b0[7] = f2bf(x0b.w);
    b1[0] = f2bf(x1a.x); b1[1] = f2bf(x1a.y); b1[2] = f2bf(x1a.z); b1[3] = f2bf(x1a.w);
    b1[4] = f2bf(x1b.x); b1[5] = f2bf(x1b.y); b1[6] = f2bf(x1b.z); b1[7] = f2bf(x1b.w);

    // staging chunks: c -> logical (row=c>>3, g=c&7), phys short-offset = row*64 + (g^(row&7))*8
    int c0 = tid, c1 = tid + 256;
    int p0s = (c0 >> 3) * 64 + (((c0 & 7) ^ ((c0 >> 3) & 7)) << 3);
    int p1s = (c1 >> 3) * 64 + (((c1 & 7) ^ ((c1 >> 3) & 7)) << 3);

    {
        const int4* src = (const int4*)w1T;
        int4 v0 = src[c0], v1 = src[c1];
        *(int4*)&wbuf[0][p0s] = v0;
        *(int4*)&wbuf[0][p1s] = v1;
    }
    __syncthreads();

    for (int w = 0; w < 17; w++) {
        int cur = w & 1;
        if (w < 16) {
            const int4* src = (const int4*)w1T + (w + 1) * 512;
            int4 v0 = src[c0], v1 = src[c1];
            *(int4*)&wbuf[cur ^ 1][p0s] = v0;
            *(int4*)&wbuf[cur ^ 1][p1s] = v1;
        }
        #pragma unroll
        for (int ct = 0; ct < 4; ct++) {
            int ro = ct * 16 + m;
            int pa = q ^ (ro & 7);
            int pb = (4 + q) ^ (ro & 7);
            s8v A0 = *(const s8v*)&wbuf[cur][ro * 64 + pa * 8];
            s8v A1 = *(const s8v*)&wbuf[cur][ro * 64 + pb * 8];
            f4v acc = (f4v){0.f, 0.f, 0.f, 0.f};
            acc = __builtin_amdgcn_mfma_f32_16x16x32_bf16(A0, b0, acc, 0, 0, 0);
            acc = __builtin_amdgcn_mfma_f32_16x16x32_bf16(A1, b1, acc, 0, 0, 0);
            ushort4 o4;
            o4.x = f2bf(acc[0]); o4.y = f2bf(acc[1]); o4.z = f2bf(acc[2]); o4.w = f2bf(acc[3]);
            int g = ct * 2 + (q >> 1);
            int pg = g ^ (m & 7);
            *(ushort4*)&ou[wv][m * 64 + pg * 8 + (q & 1) * 4] = o4;
        }
        if (active) {
            int r1 = lane >> 3, g1 = lane & 7;
            int pg1 = g1 ^ (r1 & 7);
            int4 d0 = *(const int4*)&ou[wv][r1 * 64 + pg1 * 8];
            int4 d1 = *(const int4*)&ou[wv][(r1 + 8) * 64 + pg1 * 8];
            unsigned short* base = (w < 16) ? (t1 + ((size_t)w * N_NODES + nb) * 64)
                                            : (h + (size_t)nb * 64);
            *(int4*)(base + lane * 8) = d0;
            *(int4*)(base + 512 + lane * 8) = d1;
        }
        __syncthreads();
    }
}

// ---------------- scan stage 1: deg[n] = sum_t counts[n*16+t] (contiguous) ----------------
__global__ __launch_bounds__(256) void k_scan_local(const int* __restrict__ counts,
                                                    int* __restrict__ offsets,
                                                    int* __restrict__ bsum) {
    __shared__ int s[256];
    int t = threadIdx.x;
    int i = blockIdx.x * 256 + t;
    int v = 0;
    if (i < N_NODES) {
        const int4* c4 = (const int4*)(counts + i * 16);
        #pragma unroll
        for (int j = 0; j < 4; j++) {
            int4 cv = c4[j];
            v += cv.x + cv.y + cv.z + cv.w;
        }
    }
    s[t] = v;
    __syncthreads();
    #pragma unroll
    for (int off = 1; off < 256; off <<= 1) {
        int x = (t >= off) ? s[t - off] : 0;
        __syncthreads();
        s[t] += x;
        __syncthreads();
    }
    if (i < N_NODES) offsets[i] = s[t] - v;
    if (t == 255) bsum[blockIdx.x] = s[255];
}

// ---------------- scan stage 2 ----------------
__global__ __launch_bounds__(256) void k_scan_bsum(int* __restrict__ bsum) {
    __shared__ int s[256];
    int t = threadIdx.x;
    int v = (t < N_SBLK) ? bsum[t] : 0;
    s[t] = v;
    __syncthreads();
    #pragma unroll
    for (int off = 1; off < 256; off <<= 1) {
        int x = (t >= off) ? s[t - off] : 0;
        __syncthreads();
        s[t] += x;
        __syncthreads();
    }
    if (t < N_SBLK) bsum[t] = s[t] - v;
}

// ---------------- scan stage 3 ----------------
__global__ __launch_bounds__(256) void k_scan_final(int* __restrict__ offsets,
                                                    const int* __restrict__ bsum,
                                                    int* __restrict__ cursor) {
    int i = blockIdx.x * 256 + threadIdx.x;
    if (i < N_NODES) {
        int o = offsets[i] + bsum[blockIdx.x];
        offsets[i] = o;
        cursor[i] = o;
    }
    if (i == 0) offsets[N_NODES] = N_EDGES;
}

// ---------------- scatter: 4 B packed entries (t<<16)|src, no counts read ----------------
__global__ __launch_bounds__(256) void k_scatter(const int* __restrict__ ei, const int* __restrict__ et,
                                                 int* __restrict__ cursor,
                                                 int* __restrict__ sed) {
    int e = blockIdx.x * 256 + threadIdx.x;
    if (e >= N_EDGES) return;
    int src = ei[e];
    int dst = ei[N_EDGES + e];
    int t = et[e];
    int pos = atomicAdd(&cursor[dst], 1);
    sed[pos] = (t << 16) | src;
}

// ---------------- layer-1 aggregation: 1 wave/node, 8 edges in flight ----------------
__global__ __launch_bounds__(256) void k_agg1(const int* __restrict__ offsets,
                                              const int* __restrict__ sed,
                                              const int* __restrict__ counts,
                                              const unsigned short* __restrict__ t1,
                                              unsigned short* __restrict__ h) {
    int tid = threadIdx.x;
    int n = blockIdx.x * 4 + (tid >> 6);
    int lane = tid & 63;
    int slot = lane >> 3;     // edge slot 0..7
    int d8 = lane & 7;        // dim group: 8 bf16 each
    int start = offsets[n];
    int end = offsets[n + 1];
    const int* cnt = counts + n * 16;   // one L1-hot line per node
    float a[8];
    #pragma unroll
    for (int j = 0; j < 8; j++) a[j] = 0.f;
    for (int i = start + slot; i < end; i += 8) {
        int en = sed[i];
        int t = en >> 16, src = en & 0xFFFF;
        float inv = 1.0f / (float)cnt[t];
        const unsigned short* row = t1 + ((size_t)(t * N_NODES + src)) * 64 + d8 * 8;
        ushort4 v0 = *(const ushort4*)(row);
        ushort4 v1 = *(const ushort4*)(row + 4);
        a[0] += inv * bf2f(v0.x); a[1] += inv * bf2f(v0.y);
        a[2] += inv * bf2f(v0.z); a[3] += inv * bf2f(v0.w);
        a[4] += inv * bf2f(v1.x); a[5] += inv * bf2f(v1.y);
        a[6] += inv * bf2f(v1.z); a[7] += inv * bf2f(v1.w);
    }
    #pragma unroll
    for (int j = 0; j < 8; j++) {
        a[j] += __shfl_xor(a[j], 8, 64);
        a[j] += __shfl_xor(a[j], 16, 64);
        a[j] += __shfl_xor(a[j], 32, 64);
    }
    if (slot == 0) {
        size_t hi = (size_t)n * 64 + d8 * 8;
        ushort4 h0 = *(const ushort4*)(h + hi);
        ushort4 h1 = *(const ushort4*)(h + hi + 4);
        ushort4 o0, o1;
        o0.x = f2bf(bf2f(h0.x) + a[0]); o0.y = f2bf(bf2f(h0.y) + a[1]);
        o0.z = f2bf(bf2f(h0.z) + a[2]); o0.w = f2bf(bf2f(h0.w) + a[3]);
        o1.x = f2bf(bf2f(h1.x) + a[4]); o1.y = f2bf(bf2f(h1.y) + a[5]);
        o1.z = f2bf(bf2f(h1.z) + a[6]); o1.w = f2bf(bf2f(h1.w) + a[7]);
        *(ushort4*)(h + hi) = o0;
        *(ushort4*)(h + hi + 4) = o1;
    }
}

// ---------------- layer-2 MFMA transform: all weights staged in LDS once, loop barrier-free ----
__global__ __launch_bounds__(256) void k_gemm2(const unsigned short* __restrict__ h,
                                               const unsigned short* __restrict__ w2T,
                                               unsigned short* __restrict__ t2, float* __restrict__ out) {
    __shared__ __align__(16) unsigned short wall[272 * 64];   // 17 slices x 16 rows x 64 k, swizzled
    int tid = threadIdx.x;
    int wv = tid >> 6, lane = tid & 63;
    int m = lane & 15, q = lane >> 4;
    int nb = blockIdx.x * 64 + wv * 16;

    for (int c = tid; c < 2176; c += 256) {
        int4 v = ((const int4*)w2T)[c];
        int row = c >> 3, g = c & 7;
        *(int4*)&wall[row * 64 + ((g ^ (row & 7)) << 3)] = v;
    }
    __syncthreads();
    if (nb >= N_NODES) return;
    int n = nb + m;

    s8v b0 = *(const s8v*)(h + (size_t)n * 64 + q * 8);
    s8v b1 = *(const s8v*)(h + (size_t)n * 64 + 32 + q * 8);
    #pragma unroll
    for (int j = 0; j < 8; j++) {
        if ((unsigned short)b0[j] & 0x8000u) b0[j] = 0;
        if ((unsigned short)b1[j] & 0x8000u) b1[j] = 0;
    }

    for (int w = 0; w < 17; w++) {
        int ro = w * 16 + m;
        int pa = q ^ (ro & 7);
        int pb = (4 + q) ^ (ro & 7);
        s8v A0 = *(const s8v*)&wall[ro * 64 + pa * 8];
        s8v A1 = *(const s8v*)&wall[ro * 64 + pb * 8];
        f4v acc = (f4v){0.f, 0.f, 0.f, 0.f};
        acc = __builtin_amdgcn_mfma_f32_16x16x32_bf16(A0, b0, acc, 0, 0, 0);
        acc = __builtin_amdgcn_mfma_f32_16x16x32_bf16(A1, b1, acc, 0, 0, 0);
        if (w < 16) {
            ushort4 o;
            o.x = f2bf(acc[0]); o.y = f2bf(acc[1]); o.z = f2bf(acc[2]); o.w = f2bf(acc[3]);
            *(ushort4*)(t2 + ((size_t)w * N_NODES + n) * 16 + q * 4) = o;
        } else {
            *(float4*)(out + (size_t)n * 16 + q * 4) = make_float4(acc[0], acc[1], acc[2], acc[3]);
        }
    }
}

// ---------------- layer-2 aggregation: 16 lanes/node, 8 edges in flight ----------------
__global__ __launch_bounds__(256) void k_agg2(const int* __restrict__ offsets,
                                              const int* __restrict__ sed,
                                              const int* __restrict__ counts,
                                              const unsigned short* __restrict__ t2,
                                              float* __restrict__ out) {
    int tid = threadIdx.x;
    int n = blockIdx.x * 16 + (tid >> 4);
    int sub = tid & 15;
    int slot = sub >> 1;      // edge slot 0..7
    int d2 = sub & 1;         // dim half: 8 bf16 each
    int start = offsets[n];
    int end = offsets[n + 1];
    const int* cnt = counts + n * 16;
    float a[8];
    #pragma unroll
    for (int j = 0; j < 8; j++) a[j] = 0.f;
    for (int i = start + slot; i < end; i += 8) {
        int en = sed[i];
        int t = en >> 16, src = en & 0xFFFF;
        float inv = 1.0f / (float)cnt[t];
        const unsigned short* row = t2 + ((size_t)(t * N_NODES + src)) * 16 + d2 * 8;
        ushort4 v0 = *(const ushort4*)(row);
        ushort4 v1 = *(const ushort4*)(row + 4);
        a[0] += inv * bf2f(v0.x); a[1] += inv * bf2f(v0.y);
        a[2] += inv * bf2f(v0.z); a[3] += inv * bf2f(v0.w);
        a[4] += inv * bf2f(v1.x); a[5] += inv * bf2f(v1.y);
        a[6] += inv * bf2f(v1.z); a[7] += inv * bf2f(v1.w);
    }
    #pragma unroll
    for (int j = 0; j < 8; j++) {
        a[j] += __shfl_xor(a[j], 2, 64);
        a[j] += __shfl_xor(a[j], 4, 64);
        a[j] += __shfl_xor(a[j], 8, 64);
    }
    if (slot == 0) {
        float* p = out + (size_t)n * 16 + d2 * 8;
        float4 c0 = *(const float4*)p;
        float4 c1 = *(const float4*)(p + 4);
        c0.x += a[0]; c0.y += a[1]; c0.z += a[2]; c0.w += a[3];
        c1.x += a[4]; c1.y += a[5]; c1.z += a[6]; c1.w += a[7];
        *(float4*)p = c0;
        *(float4*)(p + 4) = c1;
    }
}

extern "C" void kernel_launch(void* const* d_in, const int* in_sizes, int n_in,
                              void* d_out, int out_size, void* d_ws, size_t ws_size,
                              hipStream_t stream) {
    const float* x      = (const float*)d_in[0];
    const float* bases1 = (const float*)d_in[1];
    const float* coeffs1= (const float*)d_in[2];
    const float* self1  = (const float*)d_in[3];
    const float* bases2 = (const float*)d_in[4];
    const float* coeffs2= (const float*)d_in[5];
    const float* self2  = (const float*)d_in[6];
    const int*   ei     = (const int*)d_in[7];
    const int*   et     = (const int*)d_in[8];
    float* out = (float*)d_out;

    char* ws = (char*)d_ws;
    int*            counts  = (int*)(ws + 0);                    //  3,200,000  (node-major [n*16+t])
    int*            offsets = (int*)(ws + 3200000);              //    200,064
    int*            cursor  = (int*)(ws + 3400064);              //    200,064
    unsigned short* w1T     = (unsigned short*)(ws + 3600128);   //    139,264  (17x64x64 bf16)
    unsigned short* w2T     = (unsigned short*)(ws + 3739392);   //     34,816  (17x16x64 bf16)
    int*            bsum    = (int*)(ws + 3774208);              //      1,024
    int*            sed     = (int*)(ws + 3775232);              //  3,200,000  (packed (t<<16)|src)
    unsigned short* h       = (unsigned short*)(ws + 6975232);   //  6,400,000
    unsigned short* t1      = (unsigned short*)(ws + 13375232);  // 102,400,000 -> end 115,775,232
    unsigned short* t2      = t1;                                // alias: t1 dead after k_agg1

    hipMemsetAsync(counts, 0, 3200000, stream);
    k_wrel<<<(17 * 4096 + 17 * 1024 + 255) / 256, 256, 0, stream>>>(
        bases1, coeffs1, self1, bases2, coeffs2, self2, w1T, w2T);
    k_fused1<<<G1_BLOCKS + CNT_BLOCKS, 256, 0, stream>>>(x, w1T, t1, h, ei, et, counts);
    k_scan_local<<<N_SBLK, 256, 0, stream>>>(counts, offsets, bsum);
    k_scan_bsum<<<1, 256, 0, stream>>>(bsum);
    k_scan_final<<<N_SBLK, 256, 0, stream>>>(offsets, bsum, cursor);
    k_scatter<<<(N_EDGES + 255) / 256, 256, 0, stream>>>(ei, et, cursor, sed);
    k_agg1<<<12500, 256, 0, stream>>>(offsets, sed, counts, t1, h);
    k_gemm2<<<(N_NODES + 63) / 64, 256, 0, stream>>>(h, w2T, t2, out);
    k_agg2<<<3125, 256, 0, stream>>>(offsets, sed, counts, t2, out);
}

// Round 10
// 222.201 us; speedup vs baseline: 1.0993x; 1.0993x over previous
//
#include <hip/hip_runtime.h>

#define N_NODES 50000
#define N_REL 16
#define N_BASIS 8
#define D_IN 64
#define D_HID 64
#define N_CLASS 16
#define N_EDGES 800000
#define N_SBLK 196        // ceil(50000/256)
#define G1_BLOCKS 782     // ceil(50000/64)
#define CNT_BLOCKS 3125   // ceil(800000/256)
#define WREL_BLOCKS 340   // (17*4096 + 17*1024)/256

typedef short s8v __attribute__((ext_vector_type(8)));    // 8 bf16 (4 VGPRs) MFMA A/B frag
typedef float f4v __attribute__((ext_vector_type(4)));    // 4 fp32 MFMA C/D frag

__device__ inline unsigned short f2bf(float f) {
    union { float f; unsigned u; } v; v.f = f;
    unsigned r = (v.u + 0x7FFFu + ((v.u >> 16) & 1u)) >> 16;   // RNE
    return (unsigned short)r;
}
__device__ inline float bf2f(unsigned short b) {
    union { unsigned u; float f; } v; v.u = ((unsigned)b) << 16;
    return v.f;
}

// ---------------- FUSED pre-pass: wrel (blocks 0..339) || counts histogram (rest) ----------------
// counts node-major: counts[dst*16+t]
__global__ __launch_bounds__(256) void k_pre(const float* __restrict__ b1, const float* __restrict__ c1,
                                             const float* __restrict__ s1f,
                                             const float* __restrict__ b2, const float* __restrict__ c2,
                                             const float* __restrict__ s2f,
                                             unsigned short* __restrict__ w1T,
                                             unsigned short* __restrict__ w2T,
                                             const int* __restrict__ ei,
                                             const int* __restrict__ et,
                                             int* __restrict__ counts) {
    if (blockIdx.x >= WREL_BLOCKS) {
        int e = (blockIdx.x - WREL_BLOCKS) * 256 + threadIdx.x;
        if (e < N_EDGES) {
            int dst = ei[N_EDGES + e];
            int t = et[e];
            atomicAdd(&counts[dst * 16 + t], 1);
        }
        return;
    }
    int idx = blockIdx.x * 256 + threadIdx.x;
    if (idx < 17 * 4096) {
        int r = idx >> 12;            // 0..16
        int o = (idx >> 6) & 63;
        int k = idx & 63;
        float acc = 0.f;
        if (r < 16) {
            #pragma unroll
            for (int b = 0; b < N_BASIS; b++) acc += c1[r * N_BASIS + b] * b1[b * 4096 + k * 64 + o];
        } else {
            acc = s1f[k * 64 + o];
        }
        w1T[idx] = f2bf(acc);
    } else {
        int idx2 = idx - 17 * 4096;
        if (idx2 < 17 * 1024) {
            int r = idx2 >> 10;       // 0..16
            int o = (idx2 >> 6) & 15;
            int k = idx2 & 63;
            float acc = 0.f;
            if (r < 16) {
                #pragma unroll
                for (int b = 0; b < N_BASIS; b++) acc += c2[r * N_BASIS + b] * b2[b * 1024 + k * 16 + o];
            } else {
                acc = s2f[k * 16 + o];
            }
            w2T[idx2] = f2bf(acc);
        }
    }
}

// ---------------- scan stage 1: deg[n] = sum_t counts[n*16+t] (contiguous) ----------------
__global__ __launch_bounds__(256) void k_scan_local(const int* __restrict__ counts,
                                                    int* __restrict__ offsets,
                                                    int* __restrict__ bsum) {
    __shared__ int s[256];
    int t = threadIdx.x;
    int i = blockIdx.x * 256 + t;
    int v = 0;
    if (i < N_NODES) {
        const int4* c4 = (const int4*)(counts + i * 16);
        #pragma unroll
        for (int j = 0; j < 4; j++) {
            int4 cv = c4[j];
            v += cv.x + cv.y + cv.z + cv.w;
        }
    }
    s[t] = v;
    __syncthreads();
    #pragma unroll
    for (int off = 1; off < 256; off <<= 1) {
        int x = (t >= off) ? s[t - off] : 0;
        __syncthreads();
        s[t] += x;
        __syncthreads();
    }
    if (i < N_NODES) offsets[i] = s[t] - v;
    if (t == 255) bsum[blockIdx.x] = s[255];
}

// ---------------- scan stage 2 ----------------
__global__ __launch_bounds__(256) void k_scan_bsum(int* __restrict__ bsum) {
    __shared__ int s[256];
    int t = threadIdx.x;
    int v = (t < N_SBLK) ? bsum[t] : 0;
    s[t] = v;
    __syncthreads();
    #pragma unroll
    for (int off = 1; off < 256; off <<= 1) {
        int x = (t >= off) ? s[t - off] : 0;
        __syncthreads();
        s[t] += x;
        __syncthreads();
    }
    if (t < N_SBLK) bsum[t] = s[t] - v;
}

// ---------------- scan stage 3 ----------------
__global__ __launch_bounds__(256) void k_scan_final(int* __restrict__ offsets,
                                                    const int* __restrict__ bsum,
                                                    int* __restrict__ cursor) {
    int i = blockIdx.x * 256 + threadIdx.x;
    if (i < N_NODES) {
        int o = offsets[i] + bsum[blockIdx.x];
        offsets[i] = o;
        cursor[i] = o;
    }
    if (i == 0) offsets[N_NODES] = N_EDGES;
}

// ---------------- FUSED: layer-1 MFMA transform (blocks 0..781) || scatter (rest) ----------------
// Both independent: gemm1 needs x,w1T; scatter needs cursor (ready) + ei/et/counts.
// sed entries 8 B: ((t<<16)|src, inv_bits) — R8-proven granularity.
__global__ __launch_bounds__(256) void k_fused1(const float* __restrict__ x,
                                                const unsigned short* __restrict__ w1T,
                                                unsigned short* __restrict__ t1,
                                                unsigned short* __restrict__ h,
                                                const int* __restrict__ ei,
                                                const int* __restrict__ et,
                                                const int* __restrict__ counts,
                                                int* __restrict__ cursor,
                                                int2* __restrict__ sed) {
    if (blockIdx.x >= G1_BLOCKS) {
        int e = (blockIdx.x - G1_BLOCKS) * 256 + threadIdx.x;
        if (e < N_EDGES) {
            int src = ei[e];
            int dst = ei[N_EDGES + e];
            int t = et[e];
            int pos = atomicAdd(&cursor[dst], 1);
            float inv = 1.0f / (float)counts[dst * 16 + t];
            sed[pos] = make_int2((t << 16) | src, __float_as_int(inv));
        }
        return;
    }
    __shared__ __align__(16) unsigned short wbuf[2][64 * 64];   // 2 x 8 KB weight slices
    __shared__ __align__(16) unsigned short ou[4][16 * 64];     // per-wave epilogue tiles
    int tid = threadIdx.x;
    int wv = tid >> 6, lane = tid & 63;
    int m = lane & 15, q = lane >> 4;
    int nb = blockIdx.x * 64 + wv * 16;
    bool active = (nb < N_NODES);        // wave-uniform; inactive waves still hit barriers
    int n = active ? (nb + m) : 0;

    // B-fragments: x[n][k] fp32 -> bf16 in regs (held across all 17 weights)
    const float* xr = x + (size_t)n * 64 + q * 8;
    float4 x0a = *(const float4*)(xr);
    float4 x0b = *(const float4*)(xr + 4);
    float4 x1a = *(const float4*)(xr + 32);
    float4 x1b = *(const float4*)(xr + 36);
    s8v b0, b1;
    b0[0] = f2bf(x0a.x); b0[1] = f2bf(x0a.y); b0[2] = f2bf(x0a.z); b0[3] = f2bf(x0a.w);
    b0[4] = f2bf(x0b.x); b0[5] = f2bf(x0b.y); b0[6] = f2bf(x0b.z); b0[7] = f2bf(x0b.w);
    b1[0] = f2bf(x1a.x); b1[1] = f2bf(x1a.y); b1[2] = f2bf(x1a.z); b1[3] = f2bf(x1a.w);
    b1[4] = f2bf(x1b.x); b1[5] = f2bf(x1b.y); b1[6] = f2bf(x1b.z); b1[7] = f2bf(x1b.w);

    // staging chunks: c -> (row=c>>3, g=c&7), phys short-offset = row*64 + (g^(row&7))*8
    int c0 = tid, c1 = tid + 256;
    int p0s = (c0 >> 3) * 64 + (((c0 & 7) ^ ((c0 >> 3) & 7)) << 3);
    int p1s = (c1 >> 3) * 64 + (((c1 & 7) ^ ((c1 >> 3) & 7)) << 3);

    {
        const int4* src = (const int4*)w1T;
        int4 v0 = src[c0], v1 = src[c1];
        *(int4*)&wbuf[0][p0s] = v0;
        *(int4*)&wbuf[0][p1s] = v1;
    }
    __syncthreads();

    for (int w = 0; w < 17; w++) {
        int cur = w & 1;
        if (w < 16) {
            const int4* src = (const int4*)w1T + (w + 1) * 512;
            int4 v0 = src[c0], v1 = src[c1];
            *(int4*)&wbuf[cur ^ 1][p0s] = v0;
            *(int4*)&wbuf[cur ^ 1][p1s] = v1;
        }
        #pragma unroll
        for (int ct = 0; ct < 4; ct++) {
            int ro = ct * 16 + m;
            int pa = q ^ (ro & 7);
            int pb = (4 + q) ^ (ro & 7);
            s8v A0 = *(const s8v*)&wbuf[cur][ro * 64 + pa * 8];
            s8v A1 = *(const s8v*)&wbuf[cur][ro * 64 + pb * 8];
            f4v acc = (f4v){0.f, 0.f, 0.f, 0.f};
            acc = __builtin_amdgcn_mfma_f32_16x16x32_bf16(A0, b0, acc, 0, 0, 0);
            acc = __builtin_amdgcn_mfma_f32_16x16x32_bf16(A1, b1, acc, 0, 0, 0);
            ushort4 o4;
            o4.x = f2bf(acc[0]); o4.y = f2bf(acc[1]); o4.z = f2bf(acc[2]); o4.w = f2bf(acc[3]);
            int g = ct * 2 + (q >> 1);
            int pg = g ^ (m & 7);
            *(ushort4*)&ou[wv][m * 64 + pg * 8 + (q & 1) * 4] = o4;
        }
        if (active) {
            int r1 = lane >> 3, g1 = lane & 7;
            int pg1 = g1 ^ (r1 & 7);
            int4 d0 = *(const int4*)&ou[wv][r1 * 64 + pg1 * 8];
            int4 d1 = *(const int4*)&ou[wv][(r1 + 8) * 64 + pg1 * 8];
            unsigned short* base = (w < 16) ? (t1 + ((size_t)w * N_NODES + nb) * 64)
                                            : (h + (size_t)nb * 64);
            *(int4*)(base + lane * 8) = d0;
            *(int4*)(base + 512 + lane * 8) = d1;
        }
        __syncthreads();
    }
}

// ---------------- layer-1 aggregation: 1 wave/node, 8 slots x unroll-2 = 16 rows in flight ----
__global__ __launch_bounds__(256) void k_agg1(const int* __restrict__ offsets,
                                              const int2* __restrict__ sed,
                                              const unsigned short* __restrict__ t1,
                                              unsigned short* __restrict__ h) {
    int tid = threadIdx.x;
    int n = blockIdx.x * 4 + (tid >> 6);
    int lane = tid & 63;
    int slot = lane >> 3;     // edge slot 0..7
    int d8 = lane & 7;        // dim group: 8 bf16 each
    int start = offsets[n];
    int end = offsets[n + 1];
    float a[8];
    #pragma unroll
    for (int j = 0; j < 8; j++) a[j] = 0.f;
    for (int i = start + slot; i < end; i += 16) {
        int2 e0 = sed[i];
        bool has1 = (i + 8) < end;
        int2 e1 = has1 ? sed[i + 8] : e0;
        float inv0 = __int_as_float(e0.y);
        float inv1 = has1 ? __int_as_float(e1.y) : 0.f;
        int id0 = e0.x, id1 = e1.x;
        const unsigned short* r0 = t1 + ((size_t)((id0 >> 16) * N_NODES + (id0 & 0xFFFF))) * 64 + d8 * 8;
        const unsigned short* r1 = t1 + ((size_t)((id1 >> 16) * N_NODES + (id1 & 0xFFFF))) * 64 + d8 * 8;
        ushort4 v00 = *(const ushort4*)(r0);
        ushort4 v01 = *(const ushort4*)(r0 + 4);
        ushort4 v10 = *(const ushort4*)(r1);
        ushort4 v11 = *(const ushort4*)(r1 + 4);
        a[0] += inv0 * bf2f(v00.x); a[1] += inv0 * bf2f(v00.y);
        a[2] += inv0 * bf2f(v00.z); a[3] += inv0 * bf2f(v00.w);
        a[4] += inv0 * bf2f(v01.x); a[5] += inv0 * bf2f(v01.y);
        a[6] += inv0 * bf2f(v01.z); a[7] += inv0 * bf2f(v01.w);
        a[0] += inv1 * bf2f(v10.x); a[1] += inv1 * bf2f(v10.y);
        a[2] += inv1 * bf2f(v10.z); a[3] += inv1 * bf2f(v10.w);
        a[4] += inv1 * bf2f(v11.x); a[5] += inv1 * bf2f(v11.y);
        a[6] += inv1 * bf2f(v11.z); a[7] += inv1 * bf2f(v11.w);
    }
    #pragma unroll
    for (int j = 0; j < 8; j++) {
        a[j] += __shfl_xor(a[j], 8, 64);
        a[j] += __shfl_xor(a[j], 16, 64);
        a[j] += __shfl_xor(a[j], 32, 64);
    }
    if (slot == 0) {
        size_t hi = (size_t)n * 64 + d8 * 8;
        ushort4 h0 = *(const ushort4*)(h + hi);
        ushort4 h1 = *(const ushort4*)(h + hi + 4);
        ushort4 o0, o1;
        o0.x = f2bf(bf2f(h0.x) + a[0]); o0.y = f2bf(bf2f(h0.y) + a[1]);
        o0.z = f2bf(bf2f(h0.z) + a[2]); o0.w = f2bf(bf2f(h0.w) + a[3]);
        o1.x = f2bf(bf2f(h1.x) + a[4]); o1.y = f2bf(bf2f(h1.y) + a[5]);
        o1.z = f2bf(bf2f(h1.z) + a[6]); o1.w = f2bf(bf2f(h1.w) + a[7]);
        *(ushort4*)(h + hi) = o0;
        *(ushort4*)(h + hi + 4) = o1;
    }
}

// ---------------- layer-2 MFMA transform: all weights staged in LDS once, loop barrier-free ----
__global__ __launch_bounds__(256) void k_gemm2(const unsigned short* __restrict__ h,
                                               const unsigned short* __restrict__ w2T,
                                               unsigned short* __restrict__ t2, float* __restrict__ out) {
    __shared__ __align__(16) unsigned short wall[272 * 64];   // 17 slices x 16 rows x 64 k, swizzled
    int tid = threadIdx.x;
    int wv = tid >> 6, lane = tid & 63;
    int m = lane & 15, q = lane >> 4;
    int nb = blockIdx.x * 64 + wv * 16;

    for (int c = tid; c < 2176; c += 256) {
        int4 v = ((const int4*)w2T)[c];
        int row = c >> 3, g = c & 7;
        *(int4*)&wall[row * 64 + ((g ^ (row & 7)) << 3)] = v;
    }
    __syncthreads();
    if (nb >= N_NODES) return;
    int n = nb + m;

    s8v b0 = *(const s8v*)(h + (size_t)n * 64 + q * 8);
    s8v b1 = *(const s8v*)(h + (size_t)n * 64 + 32 + q * 8);
    #pragma unroll
    for (int j = 0; j < 8; j++) {
        if ((unsigned short)b0[j] & 0x8000u) b0[j] = 0;
        if ((unsigned short)b1[j] & 0x8000u) b1[j] = 0;
    }

    for (int w = 0; w < 17; w++) {
        int ro = w * 16 + m;
        int pa = q ^ (ro & 7);
        int pb = (4 + q) ^ (ro & 7);
        s8v A0 = *(const s8v*)&wall[ro * 64 + pa * 8];
        s8v A1 = *(const s8v*)&wall[ro * 64 + pb * 8];
        f4v acc = (f4v){0.f, 0.f, 0.f, 0.f};
        acc = __builtin_amdgcn_mfma_f32_16x16x32_bf16(A0, b0, acc, 0, 0, 0);
        acc = __builtin_amdgcn_mfma_f32_16x16x32_bf16(A1, b1, acc, 0, 0, 0);
        if (w < 16) {
            ushort4 o;
            o.x = f2bf(acc[0]); o.y = f2bf(acc[1]); o.z = f2bf(acc[2]); o.w = f2bf(acc[3]);
            *(ushort4*)(t2 + ((size_t)w * N_NODES + n) * 16 + q * 4) = o;
        } else {
            *(float4*)(out + (size_t)n * 16 + q * 4) = make_float4(acc[0], acc[1], acc[2], acc[3]);
        }
    }
}

// ---------------- layer-2 aggregation: 16 lanes/node, 8 slots x unroll-2 ----------------
__global__ __launch_bounds__(256) void k_agg2(const int* __restrict__ offsets,
                                              const int2* __restrict__ sed,
                                              const unsigned short* __restrict__ t2,
                                              float* __restrict__ out) {
    int tid = threadIdx.x;
    int n = blockIdx.x * 16 + (tid >> 4);
    int sub = tid & 15;
    int slot = sub >> 1;      // edge slot 0..7
    int d2 = sub & 1;         // dim half: 8 bf16 each
    int start = offsets[n];
    int end = offsets[n + 1];
    float a[8];
    #pragma unroll
    for (int j = 0; j < 8; j++) a[j] = 0.f;
    for (int i = start + slot; i < end; i += 16) {
        int2 e0 = sed[i];
        bool has1 = (i + 8) < end;
        int2 e1 = has1 ? sed[i + 8] : e0;
        float inv0 = __int_as_float(e0.y);
        float inv1 = has1 ? __int_as_float(e1.y) : 0.f;
        int id0 = e0.x, id1 = e1.x;
        const unsigned short* r0 = t2 + ((size_t)((id0 >> 16) * N_NODES + (id0 & 0xFFFF))) * 16 + d2 * 8;
        const unsigned short* r1 = t2 + ((size_t)((id1 >> 16) * N_NODES + (id1 & 0xFFFF))) * 16 + d2 * 8;
        ushort4 v00 = *(const ushort4*)(r0);
        ushort4 v01 = *(const ushort4*)(r0 + 4);
        ushort4 v10 = *(const ushort4*)(r1);
        ushort4 v11 = *(const ushort4*)(r1 + 4);
        a[0] += inv0 * bf2f(v00.x); a[1] += inv0 * bf2f(v00.y);
        a[2] += inv0 * bf2f(v00.z); a[3] += inv0 * bf2f(v00.w);
        a[4] += inv0 * bf2f(v01.x); a[5] += inv0 * bf2f(v01.y);
        a[6] += inv0 * bf2f(v01.z); a[7] += inv0 * bf2f(v01.w);
        a[0] += inv1 * bf2f(v10.x); a[1] += inv1 * bf2f(v10.y);
        a[2] += inv1 * bf2f(v10.z); a[3] += inv1 * bf2f(v10.w);
        a[4] += inv1 * bf2f(v11.x); a[5] += inv1 * bf2f(v11.y);
        a[6] += inv1 * bf2f(v11.z); a[7] += inv1 * bf2f(v11.w);
    }
    #pragma unroll
    for (int j = 0; j < 8; j++) {
        a[j] += __shfl_xor(a[j], 2, 64);
        a[j] += __shfl_xor(a[j], 4, 64);
        a[j] += __shfl_xor(a[j], 8, 64);
    }
    if (slot == 0) {
        float* p = out + (size_t)n * 16 + d2 * 8;
        float4 c0 = *(const float4*)p;
        float4 c1 = *(const float4*)(p + 4);
        c0.x += a[0]; c0.y += a[1]; c0.z += a[2]; c0.w += a[3];
        c1.x += a[4]; c1.y += a[5]; c1.z += a[6]; c1.w += a[7];
        *(float4*)p = c0;
        *(float4*)(p + 4) = c1;
    }
}

extern "C" void kernel_launch(void* const* d_in, const int* in_sizes, int n_in,
                              void* d_out, int out_size, void* d_ws, size_t ws_size,
                              hipStream_t stream) {
    const float* x      = (const float*)d_in[0];
    const float* bases1 = (const float*)d_in[1];
    const float* coeffs1= (const float*)d_in[2];
    const float* self1  = (const float*)d_in[3];
    const float* bases2 = (const float*)d_in[4];
    const float* coeffs2= (const float*)d_in[5];
    const float* self2  = (const float*)d_in[6];
    const int*   ei     = (const int*)d_in[7];
    const int*   et     = (const int*)d_in[8];
    float* out = (float*)d_out;

    char* ws = (char*)d_ws;
    int*            counts  = (int*)(ws + 0);                    //  3,200,000  (node-major [n*16+t])
    int*            offsets = (int*)(ws + 3200000);              //    200,064
    int*            cursor  = (int*)(ws + 3400064);              //    200,064
    unsigned short* w1T     = (unsigned short*)(ws + 3600128);   //    139,264  (17x64x64 bf16)
    unsigned short* w2T     = (unsigned short*)(ws + 3739392);   //     34,816  (17x16x64 bf16)
    int*            bsum    = (int*)(ws + 3774208);              //      1,024
    int2*           sed     = (int2*)(ws + 3775232);             //  6,400,000  (packed id, inv)
    unsigned short* h       = (unsigned short*)(ws + 10175232);  //  6,400,000
    unsigned short* t1      = (unsigned short*)(ws + 16575232);  // 102,400,000 -> end 118,975,232
    unsigned short* t2      = t1;                                // alias: t1 dead after k_agg1

    hipMemsetAsync(counts, 0, 3200000, stream);
    k_pre<<<WREL_BLOCKS + CNT_BLOCKS, 256, 0, stream>>>(
        bases1, coeffs1, self1, bases2, coeffs2, self2, w1T, w2T, ei, et, counts);
    k_scan_local<<<N_SBLK, 256, 0, stream>>>(counts, offsets, bsum);
    k_scan_bsum<<<1, 256, 0, stream>>>(bsum);
    k_scan_final<<<N_SBLK, 256, 0, stream>>>(offsets, bsum, cursor);
    k_fused1<<<G1_BLOCKS + CNT_BLOCKS, 256, 0, stream>>>(x, w1T, t1, h, ei, et, counts, cursor, sed);
    k_agg1<<<12500, 256, 0, stream>>>(offsets, sed, t1, h);
    k_gemm2<<<(N_NODES + 63) / 64, 256, 0, stream>>>(h, w2T, t2, out);
    k_agg2<<<3125, 256, 0, stream>>>(offsets, sed, t2, out);
}